// Round 6
// baseline (189.032 us; speedup 1.0000x reference)
//
#include <hip/hip_runtime.h>
#include <hip/hip_bf16.h>
#include <string.h>

#define L 4096
#define D 256
#define H 8
#define DH 32

typedef __attribute__((ext_vector_type(8))) short bf16x8;
typedef __attribute__((ext_vector_type(4))) float f32x4;

#define LOG2E 1.4426950408889634f
#define RS (0.17677669529663688f * LOG2E)   // 1/sqrt(DH) * log2(e), folded into Q

__device__ __forceinline__ ushort f2bf(float f) {
    union { float f; unsigned int i; } v; v.f = f;
    unsigned int x = v.i;
    return (ushort)((x + 0x7fffu + ((x >> 16) & 1u)) >> 16);   // RNE
}
__device__ __forceinline__ bf16x8 cvt8(const float* p) {
    float4 a = *(const float4*)p;
    float4 b = *(const float4*)(p + 4);
    bf16x8 r;
    r[0] = (short)f2bf(a.x); r[1] = (short)f2bf(a.y);
    r[2] = (short)f2bf(a.z); r[3] = (short)f2bf(a.w);
    r[4] = (short)f2bf(b.x); r[5] = (short)f2bf(b.y);
    r[6] = (short)f2bf(b.z); r[7] = (short)f2bf(b.w);
    return r;
}
// pack two fp32 -> bf16x2 dword; native v_cvt_pk_bf16_f32 on gfx950
__device__ __forceinline__ unsigned int pkbf(float a, float b) {
    float2 t; t.x = a; t.y = b;
    __hip_bfloat162 r = __float22bfloat162_rn(t);
    unsigned int u; memcpy(&u, &r, 4);
    return u;
}
__device__ __forceinline__ float uaf(unsigned int u) {
    union { unsigned int u; float f; } v; v.u = u; return v.f;
}

// sigma: logical key u (0..63) -> K storage row within its 64-block.
__device__ __forceinline__ int ksig(int u) {
    return 32 * (u >> 5) + 16 * ((u >> 2) & 1) + 4 * ((u >> 3) & 3) + (u & 3);
}

// ---------------- Kernel 0: prepack ----------------
// m2 payload: 2x 16-bit pair byte-offsets (e_i*14+e_j)*128 into the stride-32
// replicated pair-LUT (32 copies, copy = lane&31 -> bank == lane&31, any p:
// provably conflict-free). Dword positions unchanged.
__global__ __launch_bounds__(256) void pack_kernel(
        const int* __restrict__ mask, const float* __restrict__ x,
        const float* __restrict__ wi, const float* __restrict__ wo,
        unsigned int* __restrict__ m2, ushort* __restrict__ xb,
        ushort* __restrict__ wib, ushort* __restrict__ wob)
{
    const int b = blockIdx.x;
    const int tid = threadIdx.x;
    if (b < 512) {
        __shared__ unsigned int rb[8 * 1025];
        const int4* src = (const int4*)(mask + (size_t)b * 8 * 4096);
#pragma unroll
        for (int i = 0; i < 32; i++) {
            const int g = i * 256 + tid;
            int4 v = src[g];
            rb[(g >> 10) * 1025 + (g & 1023)] =
                ((unsigned int)(v.x & 15) << 4)  | ((unsigned int)(v.y & 15) << 12) |
                ((unsigned int)(v.z & 15) << 20) | ((unsigned int)(v.w & 15) << 28);
        }
        __syncthreads();
        const int t = b >> 1, half = b & 1;
#pragma unroll
        for (int i = 0; i < 32; i++) {
            const int dd = i * 256 + tid;
            const int nt = dd & 3, s = (dd >> 2) & 7, qd = (dd >> 5) & 3, kt = dd >> 7;
            const unsigned int w =
                rb[s * 1025 + kt * 16 + 8 * (nt >> 1) + 2 * qd + (nt & 1)];
            const unsigned int e0 = (w >> 4) & 15u, e1 = (w >> 12) & 15u;
            const unsigned int e2 = (w >> 20) & 15u, e3 = w >> 28;
            const unsigned int p01 = e0 * 14u + e1, p23 = e2 * 14u + e3;
            m2[(size_t)t * 16384 + kt * 256 + (qd * 16 + 8 * half + s) * 4 + nt] =
                (p01 * 128u) | ((p23 * 128u) << 16);
        }
    } else if (b < 1024) {
        const int t = (b - 512) * 256 + tid;
        ((bf16x8*)xb)[t] = cvt8(x + t * 8);
    } else if (b < 1120) {
        const int t = (b - 1024) * 256 + tid;
        ((bf16x8*)wib)[t] = cvt8(wi + t * 8);
    } else {
        const int t = (b - 1120) * 256 + tid;
        ((bf16x8*)wob)[t] = cvt8(wo + t * 8);
    }
}

// ---------------- Kernel 1: QKV projection ----------------
__global__ __launch_bounds__(256) void qkv_kernel(
        const ushort* __restrict__ xb, const ushort* __restrict__ wb,
        const float* __restrict__ b,
        ushort* __restrict__ Qb, ushort* __restrict__ Kb, ushort* __restrict__ Vt)
{
    const int lane = threadIdx.x & 63, wv = threadIdx.x >> 6;
    const int quad = lane >> 4, l15 = lane & 15;
    const int m0 = blockIdx.x * 64 + wv * 16;
    const int n0 = blockIdx.y * 64;

    f32x4 acc[4] = {};
    for (int ks = 0; ks < 8; ks++) {
        const int kd = ks * 32 + quad * 8;
        bf16x8 af = *(const bf16x8*)(xb + (m0 + l15) * D + kd);
#pragma unroll
        for (int nt = 0; nt < 4; nt++) {
            bf16x8 bfr = *(const bf16x8*)(wb + (n0 + nt * 16 + l15) * D + kd);
            acc[nt] = __builtin_amdgcn_mfma_f32_16x16x32_bf16(af, bfr, acc[nt], 0, 0, 0);
        }
    }
#pragma unroll
    for (int nt = 0; nt < 4; nt++) {
        const int j = n0 + nt * 16 + l15;
        const float bias = b[j];
#pragma unroll
        for (int r = 0; r < 4; r++) {
            const int row = m0 + quad * 4 + r;
            const float val = acc[nt][r] + bias;
            if (j < 256) {
                Qb[((j >> 5) * L + row) * DH + (j & 31)] = f2bf(val * RS);
            } else if (j < 512) {
                const int jj = j - 256;
                const int srow = (row & ~63) + ksig(row & 63);
                Kb[((jj >> 5) * L + srow) * DH + (jj & 31)] = f2bf(val);
            } else {
                const int jj = j - 512;
                Vt[((jj >> 5) * DH + (jj & 31)) * L + row] = f2bf(val);
            }
        }
    }
}

// ---------------- Kernel 2: register-resident flash attention ----------------
// R4 lesson: no pipe is >20% of elapsed -> memory-latency-bound, not conflict/
// occupancy-bound. Three latency attacks:
//  (1) head-per-XCD decode: h = bid&7 -> each XCD's L2 holds ONE head's K/V
//      (512 KB, resident). Old decode put all 8 heads (4 MB) + m2 stream in
//      each L2 -> thrash (FETCH showed K/V re-fetched ~7x).
//  (2) m2 register double-buffer: kt+1's masks load at loop top, consumed next
//      iteration -> ~500cyc m2 latency off the critical path.
//  (3) stride-32 LUT replication: bank == lane&31 for ANY pair index ->
//      provably conflict-free (R3/R4 strides were not).
__global__ __launch_bounds__(512) void attn_kernel(
        const ushort* __restrict__ Qb, const ushort* __restrict__ Kb,
        const ushort* __restrict__ Vt, const unsigned char* __restrict__ m2,
        const float* __restrict__ edge_bias, ushort* __restrict__ Ob)
{
    __shared__ unsigned int lutp[196 * 32];   // 25.1 KB pair-LUT (bf16x2)
    __shared__ float red[7 * 320];            // 9.0 KB reduction slots (4-phase)

    const int tid = threadIdx.x;
    const int lane = tid & 63, wv = tid >> 6;
    const int quad = lane >> 4, l15 = lane & 15;

    // head-per-XCD: bid%8 -> XCD; one head per XCD, K/V L2-resident.
    const int bid = blockIdx.x;
    const int h  = bid & 7;
    const int qg = bid >> 3;                   // q-group 0..127, q0 = qg*32
    const int q0 = qg * 32;
    const int kt0 = wv * 8;                    // this wave's 8-kt slice

    // per-head pair-LUT: entry p, copy c at dword p*32+c.
    for (int i = tid; i < 196 * 32; i += 512) {
        const int p = i >> 5;
        const int e1 = (p * 2341) >> 15;       // p / 14 for p < 196
        const int e2 = p - 14 * e1;
        lutp[i] = pkbf(edge_bias[e1 * H + h] * LOG2E,
                       edge_bias[e2 * H + h] * LOG2E);
    }
    __syncthreads();

    const bf16x8 qfA = *(const bf16x8*)(Qb + (h * L + q0 + l15) * DH + quad * 8);
    const bf16x8 qfB = *(const bf16x8*)(Qb + (h * L + q0 + 16 + l15) * DH + quad * 8);
    const char* lutb = (const char*)lutp + (lane & 31) * 4;   // per-lane copy base

    const ushort* Kl = Kb + h * L * DH + kt0 * 64 * DH + l15 * DH + quad * 8;
    const ushort* Va = Vt + (h * DH + l15) * L + kt0 * 64 + quad * 8;
    const ushort* Vb = Vt + (h * DH + 16 + l15) * L + kt0 * 64 + quad * 8;
    const unsigned char* mpA = m2 + (size_t)(2 * qg) * 65536
                             + (size_t)kt0 * 1024 + lane * 16;
    const unsigned char* mpB = mpA + 65536;

    f32x4 o0A = {}, o1A = {}, osA = {};
    f32x4 o0B = {}, o1B = {}, osB = {};
    bf16x8 ones;
#pragma unroll
    for (int i = 0; i < 8; i++) ones[i] = (short)0x3F80;   // 1.0 bf16

    // m2 register double-buffer (prefetch depth 1)
    int4 mA4 = *(const int4*)(mpA);
    int4 mB4 = *(const int4*)(mpB);

    for (int kt = 0; kt < 8; kt++) {
        const int nk = (kt + 1) & 7;           // kt=7 reloads 0: harmless
        const int4 nA4 = *(const int4*)(mpA + nk * 1024);
        const int4 nB4 = *(const int4*)(mpB + nk * 1024);
        const unsigned int mA[4] = {(unsigned int)mA4.x, (unsigned int)mA4.y,
                                    (unsigned int)mA4.z, (unsigned int)mA4.w};
        const unsigned int mB[4] = {(unsigned int)mB4.x, (unsigned int)mB4.y,
                                    (unsigned int)mB4.z, (unsigned int)mB4.w};

#pragma unroll
        for (int half = 0; half < 2; half++) {
            union { bf16x8 v; unsigned int u[4]; } pfA, pfB;
#pragma unroll
            for (int nt2 = 0; nt2 < 2; nt2++) {
                const int nt = half * 2 + nt2;
                bf16x8 kf = *(const bf16x8*)(Kl + (kt * 64 + nt * 16) * DH);
                f32x4 z = {};
                f32x4 svA = __builtin_amdgcn_mfma_f32_16x16x32_bf16(kf, qfA, z, 0, 0, 0);
                f32x4 svB = __builtin_amdgcn_mfma_f32_16x16x32_bf16(kf, qfB, z, 0, 0, 0);
                const unsigned int wA = mA[nt], wB = mB[nt];
                const unsigned int dA0 = *(const unsigned int*)(lutb + (wA & 0xFFFFu));
                const unsigned int dA1 = *(const unsigned int*)(lutb + (wA >> 16));
                const unsigned int dB0 = *(const unsigned int*)(lutb + (wB & 0xFFFFu));
                const unsigned int dB1 = *(const unsigned int*)(lutb + (wB >> 16));
                float a0 = __builtin_amdgcn_exp2f(svA[0] + uaf(dA0 << 16));
                float a1 = __builtin_amdgcn_exp2f(svA[1] + uaf(dA0 & 0xFFFF0000u));
                float a2 = __builtin_amdgcn_exp2f(svA[2] + uaf(dA1 << 16));
                float a3 = __builtin_amdgcn_exp2f(svA[3] + uaf(dA1 & 0xFFFF0000u));
                float b0 = __builtin_amdgcn_exp2f(svB[0] + uaf(dB0 << 16));
                float b1 = __builtin_amdgcn_exp2f(svB[1] + uaf(dB0 & 0xFFFF0000u));
                float b2 = __builtin_amdgcn_exp2f(svB[2] + uaf(dB1 << 16));
                float b3 = __builtin_amdgcn_exp2f(svB[3] + uaf(dB1 & 0xFFFF0000u));
                pfA.u[nt2 * 2]     = pkbf(a0, a1);
                pfA.u[nt2 * 2 + 1] = pkbf(a2, a3);
                pfB.u[nt2 * 2]     = pkbf(b0, b1);
                pfB.u[nt2 * 2 + 1] = pkbf(b2, b3);
            }
            bf16x8 va = *(const bf16x8*)(Va + kt * 64 + half * 32);
            bf16x8 vb = *(const bf16x8*)(Vb + kt * 64 + half * 32);
            __builtin_amdgcn_s_setprio(1);
            o0A = __builtin_amdgcn_mfma_f32_16x16x32_bf16(va,   pfA.v, o0A, 0, 0, 0);
            o1A = __builtin_amdgcn_mfma_f32_16x16x32_bf16(vb,   pfA.v, o1A, 0, 0, 0);
            osA = __builtin_amdgcn_mfma_f32_16x16x32_bf16(ones, pfA.v, osA, 0, 0, 0);
            o0B = __builtin_amdgcn_mfma_f32_16x16x32_bf16(va,   pfB.v, o0B, 0, 0, 0);
            o1B = __builtin_amdgcn_mfma_f32_16x16x32_bf16(vb,   pfB.v, o1B, 0, 0, 0);
            osB = __builtin_amdgcn_mfma_f32_16x16x32_bf16(ones, pfB.v, osB, 0, 0, 0);
            __builtin_amdgcn_s_setprio(0);
        }
        mA4 = nA4; mB4 = nB4;
    }

    // ---- 4-phase in-block KT reduction (red reused each phase) ----
    float invA, invB;
    ushort* orA = Ob + (size_t)(q0 + l15) * D + h * 32;
    ushort* orB = Ob + (size_t)(q0 + 16 + l15) * D + h * 32;
    uint2 u;
    // phase 1: o0A + osA
    if (wv > 0) {
        float* s = red + (wv - 1) * 320;
        *(f32x4*)(s + lane * 4) = o0A;
        s[256 + lane] = osA[0];
    }
    __syncthreads();
    if (wv == 0) {
#pragma unroll
        for (int sl = 0; sl < 7; sl++) {
            const float* s = red + sl * 320;
            o0A += *(const f32x4*)(s + lane * 4);
            osA[0] += s[256 + lane];
        }
        invA = 1.f / osA[0];
        u.x = pkbf(o0A[0] * invA, o0A[1] * invA);
        u.y = pkbf(o0A[2] * invA, o0A[3] * invA);
        *(uint2*)(orA + quad * 4) = u;
    }
    __syncthreads();
    // phase 2: o1A
    if (wv > 0) {
        float* s = red + (wv - 1) * 320;
        *(f32x4*)(s + lane * 4) = o1A;
    }
    __syncthreads();
    if (wv == 0) {
#pragma unroll
        for (int sl = 0; sl < 7; sl++)
            o1A += *(const f32x4*)(red + sl * 320 + lane * 4);
        u.x = pkbf(o1A[0] * invA, o1A[1] * invA);
        u.y = pkbf(o1A[2] * invA, o1A[3] * invA);
        *(uint2*)(orA + 16 + quad * 4) = u;
    }
    __syncthreads();
    // phase 3: o0B + osB
    if (wv > 0) {
        float* s = red + (wv - 1) * 320;
        *(f32x4*)(s + lane * 4) = o0B;
        s[256 + lane] = osB[0];
    }
    __syncthreads();
    if (wv == 0) {
#pragma unroll
        for (int sl = 0; sl < 7; sl++) {
            const float* s = red + sl * 320;
            o0B += *(const f32x4*)(s + lane * 4);
            osB[0] += s[256 + lane];
        }
        invB = 1.f / osB[0];
        u.x = pkbf(o0B[0] * invB, o0B[1] * invB);
        u.y = pkbf(o0B[2] * invB, o0B[3] * invB);
        *(uint2*)(orB + quad * 4) = u;
    }
    __syncthreads();
    // phase 4: o1B
    if (wv > 0) {
        float* s = red + (wv - 1) * 320;
        *(f32x4*)(s + lane * 4) = o1B;
    }
    __syncthreads();
    if (wv == 0) {
#pragma unroll
        for (int sl = 0; sl < 7; sl++)
            o1B += *(const f32x4*)(red + sl * 320 + lane * 4);
        u.x = pkbf(o1B[0] * invB, o1B[1] * invB);
        u.y = pkbf(o1B[2] * invB, o1B[3] * invB);
        *(uint2*)(orB + 16 + quad * 4) = u;
    }
}

// ---------------- Kernel 3: plain output projection GEMM ----------------
__global__ __launch_bounds__(256) void oproj_kernel(
        const ushort* __restrict__ Ob, const ushort* __restrict__ wb,
        const float* __restrict__ b, float* __restrict__ out)
{
    const int lane = threadIdx.x & 63, wv = threadIdx.x >> 6;
    const int quad = lane >> 4, l15 = lane & 15;
    const int m0 = blockIdx.x * 64 + wv * 16;
    const int n0 = blockIdx.y * 64;

    f32x4 acc[4] = {};
    for (int ks = 0; ks < 8; ks++) {
        const int kd = ks * 32 + quad * 8;
        bf16x8 af = *(const bf16x8*)(Ob + (m0 + l15) * D + kd);
#pragma unroll
        for (int nt = 0; nt < 4; nt++) {
            bf16x8 bfr = *(const bf16x8*)(wb + (n0 + nt * 16 + l15) * D + kd);
            acc[nt] = __builtin_amdgcn_mfma_f32_16x16x32_bf16(af, bfr, acc[nt], 0, 0, 0);
        }
    }
#pragma unroll
    for (int nt = 0; nt < 4; nt++) {
        const int j = n0 + nt * 16 + l15;
        const float bias = b[j];
#pragma unroll
        for (int r = 0; r < 4; r++) {
            const int orow = m0 + quad * 4 + r;
            out[orow * D + j] = acc[nt][r] + bias;
        }
    }
}

extern "C" void kernel_launch(void* const* d_in, const int* in_sizes, int n_in,
                              void* d_out, int out_size, void* d_ws, size_t ws_size,
                              hipStream_t stream) {
    const float* x     = (const float*)d_in[0];
    const int*   mask  = (const int*)d_in[1];
    const float* in_w  = (const float*)d_in[2];
    const float* in_b  = (const float*)d_in[3];
    const float* out_w = (const float*)d_in[4];
    const float* out_b = (const float*)d_in[5];
    const float* eb    = (const float*)d_in[6];

    ushort* ws = (ushort*)d_ws;
    ushort* Qb  = ws;
    ushort* Kb  = Qb + H * L * DH;             // sigma-permuted rows
    ushort* Vt  = Kb + H * L * DH;
    ushort* xb  = Vt + H * L * DH;             // x bf16 (qkv staging)
    ushort* wib = xb + L * D;
    ushort* wob = wib + 3 * D * D;
    unsigned char* m2 = (unsigned char*)(wob + D * D);   // 16 MB pair-index stream
    ushort* Ob = (ushort*)(m2 + (size_t)L * L);          // normalized bf16 attn out
    float* out = (float*)d_out;

    pack_kernel<<<dim3(1152), 256, 0, stream>>>(mask, x, in_w, out_w,
                                                (unsigned int*)m2, xb, wib, wob);
    qkv_kernel<<<dim3(64, 12), 256, 0, stream>>>(xb, wib, in_b, Qb, Kb, Vt);
    attn_kernel<<<dim3(1024), 512, 0, stream>>>(Qb, Kb, Vt, m2, eb, Ob);
    oproj_kernel<<<dim3(64, 4), 256, 0, stream>>>(Ob, wob, out_b, out);
}

// Round 7
// 186.764 us; speedup vs baseline: 1.0121x; 1.0121x over previous
//
#include <hip/hip_runtime.h>
#include <hip/hip_bf16.h>
#include <string.h>

#define L 4096
#define D 256
#define H 8
#define DH 32

typedef __attribute__((ext_vector_type(8))) short bf16x8;
typedef __attribute__((ext_vector_type(4))) float f32x4;

#define LOG2E 1.4426950408889634f
#define RS (0.17677669529663688f * LOG2E)   // 1/sqrt(DH) * log2(e), folded into Q

__device__ __forceinline__ ushort f2bf(float f) {
    union { float f; unsigned int i; } v; v.f = f;
    unsigned int x = v.i;
    return (ushort)((x + 0x7fffu + ((x >> 16) & 1u)) >> 16);   // RNE
}
__device__ __forceinline__ bf16x8 cvt8(const float* p) {
    float4 a = *(const float4*)p;
    float4 b = *(const float4*)(p + 4);
    bf16x8 r;
    r[0] = (short)f2bf(a.x); r[1] = (short)f2bf(a.y);
    r[2] = (short)f2bf(a.z); r[3] = (short)f2bf(a.w);
    r[4] = (short)f2bf(b.x); r[5] = (short)f2bf(b.y);
    r[6] = (short)f2bf(b.z); r[7] = (short)f2bf(b.w);
    return r;
}
// pack two fp32 -> bf16x2 dword; native v_cvt_pk_bf16_f32 on gfx950
__device__ __forceinline__ unsigned int pkbf(float a, float b) {
    float2 t; t.x = a; t.y = b;
    __hip_bfloat162 r = __float22bfloat162_rn(t);
    unsigned int u; memcpy(&u, &r, 4);
    return u;
}
__device__ __forceinline__ float uaf(unsigned int u) {
    union { unsigned int u; float f; } v; v.u = u; return v.f;
}

// sigma: logical key u (0..63) -> K storage row within its 64-block.
__device__ __forceinline__ int ksig(int u) {
    return 32 * (u >> 5) + 16 * ((u >> 2) & 1) + 4 * ((u >> 3) & 3) + (u & 3);
}

// ---------------- Kernel 0: prepack ----------------
// m2 payload: 2x 16-bit pair byte-offsets (e_i*14+e_j)*128 into the stride-32
// replicated pair-LUT (32 copies, copy = lane&31 -> bank == lane&31, any p:
// conflict-free, verified R6: SQ_LDS_BANK_CONFLICT = 0). Dword positions
// unchanged.
__global__ __launch_bounds__(256) void pack_kernel(
        const int* __restrict__ mask, const float* __restrict__ x,
        const float* __restrict__ wi, const float* __restrict__ wo,
        unsigned int* __restrict__ m2, ushort* __restrict__ xb,
        ushort* __restrict__ wib, ushort* __restrict__ wob)
{
    const int b = blockIdx.x;
    const int tid = threadIdx.x;
    if (b < 512) {
        __shared__ unsigned int rb[8 * 1025];
        const int4* src = (const int4*)(mask + (size_t)b * 8 * 4096);
#pragma unroll
        for (int i = 0; i < 32; i++) {
            const int g = i * 256 + tid;
            int4 v = src[g];
            rb[(g >> 10) * 1025 + (g & 1023)] =
                ((unsigned int)(v.x & 15) << 4)  | ((unsigned int)(v.y & 15) << 12) |
                ((unsigned int)(v.z & 15) << 20) | ((unsigned int)(v.w & 15) << 28);
        }
        __syncthreads();
        const int t = b >> 1, half = b & 1;
#pragma unroll
        for (int i = 0; i < 32; i++) {
            const int dd = i * 256 + tid;
            const int nt = dd & 3, s = (dd >> 2) & 7, qd = (dd >> 5) & 3, kt = dd >> 7;
            const unsigned int w =
                rb[s * 1025 + kt * 16 + 8 * (nt >> 1) + 2 * qd + (nt & 1)];
            const unsigned int e0 = (w >> 4) & 15u, e1 = (w >> 12) & 15u;
            const unsigned int e2 = (w >> 20) & 15u, e3 = w >> 28;
            const unsigned int p01 = e0 * 14u + e1, p23 = e2 * 14u + e3;
            m2[(size_t)t * 16384 + kt * 256 + (qd * 16 + 8 * half + s) * 4 + nt] =
                (p01 * 128u) | ((p23 * 128u) << 16);
        }
    } else if (b < 1024) {
        const int t = (b - 512) * 256 + tid;
        ((bf16x8*)xb)[t] = cvt8(x + t * 8);
    } else if (b < 1120) {
        const int t = (b - 1024) * 256 + tid;
        ((bf16x8*)wib)[t] = cvt8(wi + t * 8);
    } else {
        const int t = (b - 1120) * 256 + tid;
        ((bf16x8*)wob)[t] = cvt8(wo + t * 8);
    }
}

// ---------------- Kernel 1: QKV projection ----------------
__global__ __launch_bounds__(256) void qkv_kernel(
        const ushort* __restrict__ xb, const ushort* __restrict__ wb,
        const float* __restrict__ b,
        ushort* __restrict__ Qb, ushort* __restrict__ Kb, ushort* __restrict__ Vt)
{
    const int lane = threadIdx.x & 63, wv = threadIdx.x >> 6;
    const int quad = lane >> 4, l15 = lane & 15;
    const int m0 = blockIdx.x * 64 + wv * 16;
    const int n0 = blockIdx.y * 64;

    f32x4 acc[4] = {};
    for (int ks = 0; ks < 8; ks++) {
        const int kd = ks * 32 + quad * 8;
        bf16x8 af = *(const bf16x8*)(xb + (m0 + l15) * D + kd);
#pragma unroll
        for (int nt = 0; nt < 4; nt++) {
            bf16x8 bfr = *(const bf16x8*)(wb + (n0 + nt * 16 + l15) * D + kd);
            acc[nt] = __builtin_amdgcn_mfma_f32_16x16x32_bf16(af, bfr, acc[nt], 0, 0, 0);
        }
    }
#pragma unroll
    for (int nt = 0; nt < 4; nt++) {
        const int j = n0 + nt * 16 + l15;
        const float bias = b[j];
#pragma unroll
        for (int r = 0; r < 4; r++) {
            const int row = m0 + quad * 4 + r;
            const float val = acc[nt][r] + bias;
            if (j < 256) {
                Qb[((j >> 5) * L + row) * DH + (j & 31)] = f2bf(val * RS);
            } else if (j < 512) {
                const int jj = j - 256;
                const int srow = (row & ~63) + ksig(row & 63);
                Kb[((jj >> 5) * L + srow) * DH + (jj & 31)] = f2bf(val);
            } else {
                const int jj = j - 512;
                Vt[((jj >> 5) * DH + (jj & 31)) * L + row] = f2bf(val);
            }
        }
    }
}

// ---------------- Kernel 2: register-resident flash attention ----------------
// R6 lesson: head-per-XCD decode RAISED m2 traffic 8x (48->80 MB) and cost
// +3.6 us -> reverted to qg-grouped decode (all 8 head-blocks of a q-group on
// one XCD: m2 slice L2-shared, fetched once). Kept from R6: stride-32 LUT
// (conflicts == 0, verified) + m2 register double-buffer.
// New: edge bias enters via the QK MFMA's C operand (sv = K*Q + bias), saving
// the 8 v_add/nt2 on the VALU-issue-bound softmax path; gather addresses
// depend only on prefetched mask words so the compiler hoists them above the
// MFMAs (no added serialization).
__global__ __launch_bounds__(512) void attn_kernel(
        const ushort* __restrict__ Qb, const ushort* __restrict__ Kb,
        const ushort* __restrict__ Vt, const unsigned char* __restrict__ m2,
        const float* __restrict__ edge_bias, ushort* __restrict__ Ob)
{
    __shared__ unsigned int lutp[196 * 32];   // 25.1 KB pair-LUT (bf16x2)
    __shared__ float red[7 * 320];            // 9.0 KB reduction slots (4-phase)

    const int tid = threadIdx.x;
    const int lane = tid & 63, wv = tid >> 6;
    const int quad = lane >> 4, l15 = lane & 15;

    // qg-grouped XCD decode: all 8 heads of a q-group share bid%8 -> same XCD.
    const int bid = blockIdx.x;
    const int xr = bid & 7, j = bid >> 3;          // j in [0,128)
    const int qg = xr * 16 + (j >> 3);             // q-group 0..127, q0 = qg*32
    const int h  = j & 7;
    const int q0 = qg * 32;
    const int kt0 = wv * 8;                        // this wave's 8-kt slice

    // per-head pair-LUT: entry p, copy c at dword p*32+c.
    for (int i = tid; i < 196 * 32; i += 512) {
        const int p = i >> 5;
        const int e1 = (p * 2341) >> 15;       // p / 14 for p < 196
        const int e2 = p - 14 * e1;
        lutp[i] = pkbf(edge_bias[e1 * H + h] * LOG2E,
                       edge_bias[e2 * H + h] * LOG2E);
    }
    __syncthreads();

    const bf16x8 qfA = *(const bf16x8*)(Qb + (h * L + q0 + l15) * DH + quad * 8);
    const bf16x8 qfB = *(const bf16x8*)(Qb + (h * L + q0 + 16 + l15) * DH + quad * 8);
    const char* lutb = (const char*)lutp + (lane & 31) * 4;   // per-lane copy base

    const ushort* Kl = Kb + h * L * DH + kt0 * 64 * DH + l15 * DH + quad * 8;
    const ushort* Va = Vt + (h * DH + l15) * L + kt0 * 64 + quad * 8;
    const ushort* Vb = Vt + (h * DH + 16 + l15) * L + kt0 * 64 + quad * 8;
    const unsigned char* mpA = m2 + (size_t)(2 * qg) * 65536
                             + (size_t)kt0 * 1024 + lane * 16;
    const unsigned char* mpB = mpA + 65536;

    f32x4 o0A = {}, o1A = {}, osA = {};
    f32x4 o0B = {}, o1B = {}, osB = {};
    bf16x8 ones;
#pragma unroll
    for (int i = 0; i < 8; i++) ones[i] = (short)0x3F80;   // 1.0 bf16

    // m2 register double-buffer (prefetch depth 1)
    int4 mA4 = *(const int4*)(mpA);
    int4 mB4 = *(const int4*)(mpB);

    for (int kt = 0; kt < 8; kt++) {
        const int nk = (kt + 1) & 7;           // kt=7 reloads 0: harmless
        const int4 nA4 = *(const int4*)(mpA + nk * 1024);
        const int4 nB4 = *(const int4*)(mpB + nk * 1024);
        const unsigned int mA[4] = {(unsigned int)mA4.x, (unsigned int)mA4.y,
                                    (unsigned int)mA4.z, (unsigned int)mA4.w};
        const unsigned int mB[4] = {(unsigned int)mB4.x, (unsigned int)mB4.y,
                                    (unsigned int)mB4.z, (unsigned int)mB4.w};

#pragma unroll
        for (int half = 0; half < 2; half++) {
            union { bf16x8 v; unsigned int u[4]; } pfA, pfB;
#pragma unroll
            for (int nt2 = 0; nt2 < 2; nt2++) {
                const int nt = half * 2 + nt2;
                bf16x8 kf = *(const bf16x8*)(Kl + (kt * 64 + nt * 16) * DH);
                const unsigned int wA = mA[nt], wB = mB[nt];
                const unsigned int dA0 = *(const unsigned int*)(lutb + (wA & 0xFFFFu));
                const unsigned int dA1 = *(const unsigned int*)(lutb + (wA >> 16));
                const unsigned int dB0 = *(const unsigned int*)(lutb + (wB & 0xFFFFu));
                const unsigned int dB1 = *(const unsigned int*)(lutb + (wB >> 16));
                f32x4 cA, cB;
                cA[0] = uaf(dA0 << 16); cA[1] = uaf(dA0 & 0xFFFF0000u);
                cA[2] = uaf(dA1 << 16); cA[3] = uaf(dA1 & 0xFFFF0000u);
                cB[0] = uaf(dB0 << 16); cB[1] = uaf(dB0 & 0xFFFF0000u);
                cB[2] = uaf(dB1 << 16); cB[3] = uaf(dB1 & 0xFFFF0000u);
                f32x4 svA = __builtin_amdgcn_mfma_f32_16x16x32_bf16(kf, qfA, cA, 0, 0, 0);
                f32x4 svB = __builtin_amdgcn_mfma_f32_16x16x32_bf16(kf, qfB, cB, 0, 0, 0);
                float a0 = __builtin_amdgcn_exp2f(svA[0]);
                float a1 = __builtin_amdgcn_exp2f(svA[1]);
                float a2 = __builtin_amdgcn_exp2f(svA[2]);
                float a3 = __builtin_amdgcn_exp2f(svA[3]);
                float b0 = __builtin_amdgcn_exp2f(svB[0]);
                float b1 = __builtin_amdgcn_exp2f(svB[1]);
                float b2 = __builtin_amdgcn_exp2f(svB[2]);
                float b3 = __builtin_amdgcn_exp2f(svB[3]);
                pfA.u[nt2 * 2]     = pkbf(a0, a1);
                pfA.u[nt2 * 2 + 1] = pkbf(a2, a3);
                pfB.u[nt2 * 2]     = pkbf(b0, b1);
                pfB.u[nt2 * 2 + 1] = pkbf(b2, b3);
            }
            bf16x8 va = *(const bf16x8*)(Va + kt * 64 + half * 32);
            bf16x8 vb = *(const bf16x8*)(Vb + kt * 64 + half * 32);
            __builtin_amdgcn_s_setprio(1);
            o0A = __builtin_amdgcn_mfma_f32_16x16x32_bf16(va,   pfA.v, o0A, 0, 0, 0);
            o1A = __builtin_amdgcn_mfma_f32_16x16x32_bf16(vb,   pfA.v, o1A, 0, 0, 0);
            osA = __builtin_amdgcn_mfma_f32_16x16x32_bf16(ones, pfA.v, osA, 0, 0, 0);
            o0B = __builtin_amdgcn_mfma_f32_16x16x32_bf16(va,   pfB.v, o0B, 0, 0, 0);
            o1B = __builtin_amdgcn_mfma_f32_16x16x32_bf16(vb,   pfB.v, o1B, 0, 0, 0);
            osB = __builtin_amdgcn_mfma_f32_16x16x32_bf16(ones, pfB.v, osB, 0, 0, 0);
            __builtin_amdgcn_s_setprio(0);
        }
        mA4 = nA4; mB4 = nB4;
    }

    // ---- 4-phase in-block KT reduction (red reused each phase) ----
    float invA, invB;
    ushort* orA = Ob + (size_t)(q0 + l15) * D + h * 32;
    ushort* orB = Ob + (size_t)(q0 + 16 + l15) * D + h * 32;
    uint2 u;
    // phase 1: o0A + osA
    if (wv > 0) {
        float* s = red + (wv - 1) * 320;
        *(f32x4*)(s + lane * 4) = o0A;
        s[256 + lane] = osA[0];
    }
    __syncthreads();
    if (wv == 0) {
#pragma unroll
        for (int sl = 0; sl < 7; sl++) {
            const float* s = red + sl * 320;
            o0A += *(const f32x4*)(s + lane * 4);
            osA[0] += s[256 + lane];
        }
        invA = 1.f / osA[0];
        u.x = pkbf(o0A[0] * invA, o0A[1] * invA);
        u.y = pkbf(o0A[2] * invA, o0A[3] * invA);
        *(uint2*)(orA + quad * 4) = u;
    }
    __syncthreads();
    // phase 2: o1A
    if (wv > 0) {
        float* s = red + (wv - 1) * 320;
        *(f32x4*)(s + lane * 4) = o1A;
    }
    __syncthreads();
    if (wv == 0) {
#pragma unroll
        for (int sl = 0; sl < 7; sl++)
            o1A += *(const f32x4*)(red + sl * 320 + lane * 4);
        u.x = pkbf(o1A[0] * invA, o1A[1] * invA);
        u.y = pkbf(o1A[2] * invA, o1A[3] * invA);
        *(uint2*)(orA + 16 + quad * 4) = u;
    }
    __syncthreads();
    // phase 3: o0B + osB
    if (wv > 0) {
        float* s = red + (wv - 1) * 320;
        *(f32x4*)(s + lane * 4) = o0B;
        s[256 + lane] = osB[0];
    }
    __syncthreads();
    if (wv == 0) {
#pragma unroll
        for (int sl = 0; sl < 7; sl++) {
            const float* s = red + sl * 320;
            o0B += *(const f32x4*)(s + lane * 4);
            osB[0] += s[256 + lane];
        }
        invB = 1.f / osB[0];
        u.x = pkbf(o0B[0] * invB, o0B[1] * invB);
        u.y = pkbf(o0B[2] * invB, o0B[3] * invB);
        *(uint2*)(orB + quad * 4) = u;
    }
    __syncthreads();
    // phase 4: o1B
    if (wv > 0) {
        float* s = red + (wv - 1) * 320;
        *(f32x4*)(s + lane * 4) = o1B;
    }
    __syncthreads();
    if (wv == 0) {
#pragma unroll
        for (int sl = 0; sl < 7; sl++)
            o1B += *(const f32x4*)(red + sl * 320 + lane * 4);
        u.x = pkbf(o1B[0] * invB, o1B[1] * invB);
        u.y = pkbf(o1B[2] * invB, o1B[3] * invB);
        *(uint2*)(orB + 16 + quad * 4) = u;
    }
}

// ---------------- Kernel 3: plain output projection GEMM ----------------
__global__ __launch_bounds__(256) void oproj_kernel(
        const ushort* __restrict__ Ob, const ushort* __restrict__ wb,
        const float* __restrict__ b, float* __restrict__ out)
{
    const int lane = threadIdx.x & 63, wv = threadIdx.x >> 6;
    const int quad = lane >> 4, l15 = lane & 15;
    const int m0 = blockIdx.x * 64 + wv * 16;
    const int n0 = blockIdx.y * 64;

    f32x4 acc[4] = {};
    for (int ks = 0; ks < 8; ks++) {
        const int kd = ks * 32 + quad * 8;
        bf16x8 af = *(const bf16x8*)(Ob + (m0 + l15) * D + kd);
#pragma unroll
        for (int nt = 0; nt < 4; nt++) {
            bf16x8 bfr = *(const bf16x8*)(wb + (n0 + nt * 16 + l15) * D + kd);
            acc[nt] = __builtin_amdgcn_mfma_f32_16x16x32_bf16(af, bfr, acc[nt], 0, 0, 0);
        }
    }
#pragma unroll
    for (int nt = 0; nt < 4; nt++) {
        const int j = n0 + nt * 16 + l15;
        const float bias = b[j];
#pragma unroll
        for (int r = 0; r < 4; r++) {
            const int orow = m0 + quad * 4 + r;
            out[orow * D + j] = acc[nt][r] + bias;
        }
    }
}

extern "C" void kernel_launch(void* const* d_in, const int* in_sizes, int n_in,
                              void* d_out, int out_size, void* d_ws, size_t ws_size,
                              hipStream_t stream) {
    const float* x     = (const float*)d_in[0];
    const int*   mask  = (const int*)d_in[1];
    const float* in_w  = (const float*)d_in[2];
    const float* in_b  = (const float*)d_in[3];
    const float* out_w = (const float*)d_in[4];
    const float* out_b = (const float*)d_in[5];
    const float* eb    = (const float*)d_in[6];

    ushort* ws = (ushort*)d_ws;
    ushort* Qb  = ws;
    ushort* Kb  = Qb + H * L * DH;             // sigma-permuted rows
    ushort* Vt  = Kb + H * L * DH;
    ushort* xb  = Vt + H * L * DH;             // x bf16 (qkv staging)
    ushort* wib = xb + L * D;
    ushort* wob = wib + 3 * D * D;
    unsigned char* m2 = (unsigned char*)(wob + D * D);   // 16 MB pair-index stream
    ushort* Ob = (ushort*)(m2 + (size_t)L * L);          // normalized bf16 attn out
    float* out = (float*)d_out;

    pack_kernel<<<dim3(1152), 256, 0, stream>>>(mask, x, in_w, out_w,
                                                (unsigned int*)m2, xb, wib, wob);
    qkv_kernel<<<dim3(64, 12), 256, 0, stream>>>(xb, wib, in_b, Qb, Kb, Vt);
    attn_kernel<<<dim3(1024), 512, 0, stream>>>(Qb, Kb, Vt, m2, eb, Ob);
    oproj_kernel<<<dim3(64, 4), 256, 0, stream>>>(Ob, wob, out_b, out);
}

// Round 8
// 172.304 us; speedup vs baseline: 1.0971x; 1.0839x over previous
//
#include <hip/hip_runtime.h>
#include <hip/hip_bf16.h>
#include <string.h>

#define L 4096
#define D 256
#define H 8
#define DH 32

typedef __attribute__((ext_vector_type(8))) short bf16x8;
typedef __attribute__((ext_vector_type(4))) float f32x4;

#define LOG2E 1.4426950408889634f
#define RS (0.17677669529663688f * LOG2E)   // 1/sqrt(DH) * log2(e), folded into Q

__device__ __forceinline__ ushort f2bf(float f) {
    union { float f; unsigned int i; } v; v.f = f;
    unsigned int x = v.i;
    return (ushort)((x + 0x7fffu + ((x >> 16) & 1u)) >> 16);   // RNE
}
__device__ __forceinline__ bf16x8 cvt8(const float* p) {
    float4 a = *(const float4*)p;
    float4 b = *(const float4*)(p + 4);
    bf16x8 r;
    r[0] = (short)f2bf(a.x); r[1] = (short)f2bf(a.y);
    r[2] = (short)f2bf(a.z); r[3] = (short)f2bf(a.w);
    r[4] = (short)f2bf(b.x); r[5] = (short)f2bf(b.y);
    r[6] = (short)f2bf(b.z); r[7] = (short)f2bf(b.w);
    return r;
}
// pack two fp32 -> bf16x2 dword; native v_cvt_pk_bf16_f32 on gfx950
__device__ __forceinline__ unsigned int pkbf(float a, float b) {
    float2 t; t.x = a; t.y = b;
    __hip_bfloat162 r = __float22bfloat162_rn(t);
    unsigned int u; memcpy(&u, &r, 4);
    return u;
}
__device__ __forceinline__ float uaf(unsigned int u) {
    union { unsigned int u; float f; } v; v.u = u; return v.f;
}

// sigma: logical key u (0..63) -> K storage row within its 64-block.
__device__ __forceinline__ int ksig(int u) {
    return 32 * (u >> 5) + 16 * ((u >> 2) & 1) + 4 * ((u >> 3) & 3) + (u & 3);
}

// Fragment-major (FM) layout for MFMA operand matrices (R rows x C cols bf16):
//   elem(r,c) at ((r>>4)*(C/8) + (c>>3))*128 + (r&15)*8 + (c&7)
// A wave's 16x16x32-MFMA fragment load (16 l15-rows x 4 quad col-slices) is
// then ONE CONTIGUOUS 1KB transaction instead of 64 scattered 16B segments.
// (attn's Kb already had this property via ksig; qkv/oproj never did - the
// hidden ~50+ us of this pipeline.)

// ---------------- Kernel 0: prepack ----------------
// m2 payload: 2x 16-bit pair byte-offsets (e_i*14+e_j)*68 into the stride-17
// replicated pair-LUT (R4-proven config). xb/wib/wob written FM.
__global__ __launch_bounds__(256) void pack_kernel(
        const int* __restrict__ mask, const float* __restrict__ x,
        const float* __restrict__ wi, const float* __restrict__ wo,
        unsigned int* __restrict__ m2, ushort* __restrict__ xb,
        ushort* __restrict__ wib, ushort* __restrict__ wob)
{
    const int b = blockIdx.x;
    const int tid = threadIdx.x;
    if (b < 512) {
        __shared__ unsigned int rb[8 * 1025];
        const int4* src = (const int4*)(mask + (size_t)b * 8 * 4096);
#pragma unroll
        for (int i = 0; i < 32; i++) {
            const int g = i * 256 + tid;
            int4 v = src[g];
            rb[(g >> 10) * 1025 + (g & 1023)] =
                ((unsigned int)(v.x & 15) << 4)  | ((unsigned int)(v.y & 15) << 12) |
                ((unsigned int)(v.z & 15) << 20) | ((unsigned int)(v.w & 15) << 28);
        }
        __syncthreads();
        const int t = b >> 1, half = b & 1;
#pragma unroll
        for (int i = 0; i < 32; i++) {
            const int dd = i * 256 + tid;
            const int nt = dd & 3, s = (dd >> 2) & 7, qd = (dd >> 5) & 3, kt = dd >> 7;
            const unsigned int w =
                rb[s * 1025 + kt * 16 + 8 * (nt >> 1) + 2 * qd + (nt & 1)];
            const unsigned int e0 = (w >> 4) & 15u, e1 = (w >> 12) & 15u;
            const unsigned int e2 = (w >> 20) & 15u, e3 = w >> 28;
            const unsigned int p01 = e0 * 14u + e1, p23 = e2 * 14u + e3;
            m2[(size_t)t * 16384 + kt * 256 + (qd * 16 + 8 * half + s) * 4 + nt] =
                (p01 * 68u) | ((p23 * 68u) << 16);
        }
    } else if (b < 1024) {
        // xb FM: g enumerates (mg, kd, l); out linear = g*8 elements
        const int g = (b - 512) * 256 + tid;
        const int l = g & 15, kd = (g >> 4) & 31, mg = g >> 9;
        ((bf16x8*)xb)[g] = cvt8(x + (mg * 16 + l) * 256 + kd * 8);
    } else if (b < 1120) {
        const int g = (b - 1024) * 256 + tid;           // 768x256 FM
        const int l = g & 15, kd = (g >> 4) & 31, mg = g >> 9;
        ((bf16x8*)wib)[g] = cvt8(wi + (mg * 16 + l) * 256 + kd * 8);
    } else {
        const int g = (b - 1120) * 256 + tid;           // 256x256 FM
        const int l = g & 15, kd = (g >> 4) & 31, mg = g >> 9;
        ((bf16x8*)wob)[g] = cvt8(wo + (mg * 16 + l) * 256 + kd * 8);
    }
}

// ---------------- Kernel 1: QKV projection (FM operand loads) ----------------
__global__ __launch_bounds__(256) void qkv_kernel(
        const ushort* __restrict__ xb, const ushort* __restrict__ wb,
        const float* __restrict__ b,
        ushort* __restrict__ Qb, ushort* __restrict__ Kb, ushort* __restrict__ Vt)
{
    const int lane = threadIdx.x & 63, wv = threadIdx.x >> 6;
    const int quad = lane >> 4, l15 = lane & 15;
    const int m0 = blockIdx.x * 64 + wv * 16;
    const int n0 = blockIdx.y * 64;
    const ushort* ap = xb + (size_t)(blockIdx.x * 4 + wv) * 4096 + l15 * 8;
    const ushort* bp = wb + (size_t)(blockIdx.y * 4) * 4096 + l15 * 8;

    f32x4 acc[4] = {};
    for (int ks = 0; ks < 8; ks++) {
        const int kdi = (ks * 4 + quad) * 128;
        bf16x8 af = *(const bf16x8*)(ap + kdi);
#pragma unroll
        for (int nt = 0; nt < 4; nt++) {
            bf16x8 bfr = *(const bf16x8*)(bp + nt * 4096 + kdi);
            acc[nt] = __builtin_amdgcn_mfma_f32_16x16x32_bf16(af, bfr, acc[nt], 0, 0, 0);
        }
    }
#pragma unroll
    for (int nt = 0; nt < 4; nt++) {
        const int j = n0 + nt * 16 + l15;
        const float bias = b[j];
#pragma unroll
        for (int r = 0; r < 4; r++) {
            const int row = m0 + quad * 4 + r;
            const float val = acc[nt][r] + bias;
            if (j < 256) {
                Qb[((j >> 5) * L + row) * DH + (j & 31)] = f2bf(val * RS);
            } else if (j < 512) {
                const int jj = j - 256;
                const int srow = (row & ~63) + ksig(row & 63);
                Kb[((jj >> 5) * L + srow) * DH + (jj & 31)] = f2bf(val);
            } else {
                const int jj = j - 512;
                Vt[((jj >> 5) * DH + (jj & 31)) * L + row] = f2bf(val);
            }
        }
    }
}

// ---------------- Kernel 2: register-resident flash attention ----------------
// Inner loop = R4-proven config (59.5 us measured): stride-17 pair-LUT,
// 2-phase KT reduction, NO m2 prefetch (compiler hoists; manual dbuf proven
// -3.5us in R6/R7), bias via v_add into exp2 arg (bias-in-C forced C-register
// copies, R7). Only change vs R4: Ob written in FM layout for oproj.
__global__ __launch_bounds__(512) void attn_kernel(
        const ushort* __restrict__ Qb, const ushort* __restrict__ Kb,
        const ushort* __restrict__ Vt, const unsigned char* __restrict__ m2,
        const float* __restrict__ edge_bias, ushort* __restrict__ Ob)
{
    __shared__ unsigned int lutp[196 * 17];   // 13.3 KB pair-LUT (bf16x2)
    __shared__ float red[7 * 576];            // 16.1 KB reduction slots

    const int tid = threadIdx.x;
    const int lane = tid & 63, wv = tid >> 6;
    const int quad = lane >> 4, l15 = lane & 15;

    // qg-grouped XCD decode: all 8 heads of a q-group share bid%8 -> same XCD.
    const int bid = blockIdx.x;
    const int xr = bid & 7, j = bid >> 3;          // j in [0,128)
    const int qg = xr * 16 + (j >> 3);             // q-group 0..127, q0 = qg*32
    const int h  = j & 7;
    const int q0 = qg * 32;
    const int kt0 = wv * 8;                        // this wave's 8-kt slice

    // per-head pair-LUT: entry p, copy c at dword 17p+c
    for (int p = tid; p < 196; p += 512) {
        const int e1 = (p * 2341) >> 15;           // p / 14 for p < 196
        const int e2 = p - 14 * e1;
        const unsigned int v = pkbf(edge_bias[e1 * H + h] * LOG2E,
                                    edge_bias[e2 * H + h] * LOG2E);
#pragma unroll
        for (int c = 0; c < 17; c++) lutp[p * 17 + c] = v;
    }
    __syncthreads();

    const bf16x8 qfA = *(const bf16x8*)(Qb + (h * L + q0 + l15) * DH + quad * 8);
    const bf16x8 qfB = *(const bf16x8*)(Qb + (h * L + q0 + 16 + l15) * DH + quad * 8);
    const char* lutb = (const char*)lutp + l15 * 4;   // per-lane copy base

    const ushort* Kl = Kb + h * L * DH + kt0 * 64 * DH + l15 * DH + quad * 8;
    const ushort* Va = Vt + (h * DH + l15) * L + kt0 * 64 + quad * 8;
    const ushort* Vb = Vt + (h * DH + 16 + l15) * L + kt0 * 64 + quad * 8;
    const unsigned char* mpA = m2 + (size_t)(2 * qg) * 65536
                             + (size_t)kt0 * 1024 + lane * 16;
    const unsigned char* mpB = mpA + 65536;

    f32x4 o0A = {}, o1A = {}, osA = {};
    f32x4 o0B = {}, o1B = {}, osB = {};
    bf16x8 ones;
#pragma unroll
    for (int i = 0; i < 8; i++) ones[i] = (short)0x3F80;   // 1.0 bf16

    for (int kt = 0; kt < 8; kt++) {
        const int4 mA4 = *(const int4*)(mpA + kt * 1024);
        const int4 mB4 = *(const int4*)(mpB + kt * 1024);
        const unsigned int mA[4] = {(unsigned int)mA4.x, (unsigned int)mA4.y,
                                    (unsigned int)mA4.z, (unsigned int)mA4.w};
        const unsigned int mB[4] = {(unsigned int)mB4.x, (unsigned int)mB4.y,
                                    (unsigned int)mB4.z, (unsigned int)mB4.w};

#pragma unroll
        for (int half = 0; half < 2; half++) {
            union { bf16x8 v; unsigned int u[4]; } pfA, pfB;
#pragma unroll
            for (int nt2 = 0; nt2 < 2; nt2++) {
                const int nt = half * 2 + nt2;
                bf16x8 kf = *(const bf16x8*)(Kl + (kt * 64 + nt * 16) * DH);
                f32x4 z = {};
                f32x4 svA = __builtin_amdgcn_mfma_f32_16x16x32_bf16(kf, qfA, z, 0, 0, 0);
                f32x4 svB = __builtin_amdgcn_mfma_f32_16x16x32_bf16(kf, qfB, z, 0, 0, 0);
                const unsigned int wA = mA[nt], wB = mB[nt];
                const unsigned int dA0 = *(const unsigned int*)(lutb + (wA & 0xFFFFu));
                const unsigned int dA1 = *(const unsigned int*)(lutb + (wA >> 16));
                const unsigned int dB0 = *(const unsigned int*)(lutb + (wB & 0xFFFFu));
                const unsigned int dB1 = *(const unsigned int*)(lutb + (wB >> 16));
                float a0 = __builtin_amdgcn_exp2f(svA[0] + uaf(dA0 << 16));
                float a1 = __builtin_amdgcn_exp2f(svA[1] + uaf(dA0 & 0xFFFF0000u));
                float a2 = __builtin_amdgcn_exp2f(svA[2] + uaf(dA1 << 16));
                float a3 = __builtin_amdgcn_exp2f(svA[3] + uaf(dA1 & 0xFFFF0000u));
                float b0 = __builtin_amdgcn_exp2f(svB[0] + uaf(dB0 << 16));
                float b1 = __builtin_amdgcn_exp2f(svB[1] + uaf(dB0 & 0xFFFF0000u));
                float b2 = __builtin_amdgcn_exp2f(svB[2] + uaf(dB1 << 16));
                float b3 = __builtin_amdgcn_exp2f(svB[3] + uaf(dB1 & 0xFFFF0000u));
                pfA.u[nt2 * 2]     = pkbf(a0, a1);
                pfA.u[nt2 * 2 + 1] = pkbf(a2, a3);
                pfB.u[nt2 * 2]     = pkbf(b0, b1);
                pfB.u[nt2 * 2 + 1] = pkbf(b2, b3);
            }
            bf16x8 va = *(const bf16x8*)(Va + kt * 64 + half * 32);
            bf16x8 vb = *(const bf16x8*)(Vb + kt * 64 + half * 32);
            __builtin_amdgcn_s_setprio(1);
            o0A = __builtin_amdgcn_mfma_f32_16x16x32_bf16(va,   pfA.v, o0A, 0, 0, 0);
            o1A = __builtin_amdgcn_mfma_f32_16x16x32_bf16(vb,   pfA.v, o1A, 0, 0, 0);
            osA = __builtin_amdgcn_mfma_f32_16x16x32_bf16(ones, pfA.v, osA, 0, 0, 0);
            o0B = __builtin_amdgcn_mfma_f32_16x16x32_bf16(va,   pfB.v, o0B, 0, 0, 0);
            o1B = __builtin_amdgcn_mfma_f32_16x16x32_bf16(vb,   pfB.v, o1B, 0, 0, 0);
            osB = __builtin_amdgcn_mfma_f32_16x16x32_bf16(ones, pfB.v, osB, 0, 0, 0);
            __builtin_amdgcn_s_setprio(0);
        }
    }

    // FM Ob write addresses: row r=q0+l15 (mg=2qg), cols h*32 + {quad*4, 16+quad*4}
    ushort* obase = Ob + (size_t)(2 * qg) * 4096 + l15 * 8 + (quad & 1) * 4;
    ushort* or0A = obase + (h * 4 + (quad >> 1)) * 128;
    ushort* or1A = obase + (h * 4 + 2 + (quad >> 1)) * 128;
    ushort* or0B = or0A + 4096;
    ushort* or1B = or1A + 4096;

    // ---- two-phase in-block KT reduction (reuses red[] for A then B) ----
    if (wv > 0) {
        float* s = red + (wv - 1) * 576;
        *(f32x4*)(s +       lane * 4) = o0A;
        *(f32x4*)(s + 256 + lane * 4) = o1A;
        s[512 + lane] = osA[0];
    }
    __syncthreads();
    if (wv == 0) {
#pragma unroll
        for (int sl = 0; sl < 7; sl++) {
            const float* s = red + sl * 576;
            o0A += *(const f32x4*)(s +       lane * 4);
            o1A += *(const f32x4*)(s + 256 + lane * 4);
            osA[0] += s[512 + lane];
        }
        const float invA = 1.f / osA[0];
        uint2 u;
        u.x = pkbf(o0A[0] * invA, o0A[1] * invA);
        u.y = pkbf(o0A[2] * invA, o0A[3] * invA);
        *(uint2*)or0A = u;
        u.x = pkbf(o1A[0] * invA, o1A[1] * invA);
        u.y = pkbf(o1A[2] * invA, o1A[3] * invA);
        *(uint2*)or1A = u;
    }
    __syncthreads();
    if (wv > 0) {
        float* s = red + (wv - 1) * 576;
        *(f32x4*)(s +       lane * 4) = o0B;
        *(f32x4*)(s + 256 + lane * 4) = o1B;
        s[512 + lane] = osB[0];
    }
    __syncthreads();
    if (wv == 0) {
#pragma unroll
        for (int sl = 0; sl < 7; sl++) {
            const float* s = red + sl * 576;
            o0B += *(const f32x4*)(s +       lane * 4);
            o1B += *(const f32x4*)(s + 256 + lane * 4);
            osB[0] += s[512 + lane];
        }
        const float invB = 1.f / osB[0];
        uint2 u;
        u.x = pkbf(o0B[0] * invB, o0B[1] * invB);
        u.y = pkbf(o0B[2] * invB, o0B[3] * invB);
        *(uint2*)or0B = u;
        u.x = pkbf(o1B[0] * invB, o1B[1] * invB);
        u.y = pkbf(o1B[2] * invB, o1B[3] * invB);
        *(uint2*)or1B = u;
    }
}

// ---------------- Kernel 3: output projection GEMM (FM operand loads) --------
__global__ __launch_bounds__(256) void oproj_kernel(
        const ushort* __restrict__ Ob, const ushort* __restrict__ wb,
        const float* __restrict__ b, float* __restrict__ out)
{
    const int lane = threadIdx.x & 63, wv = threadIdx.x >> 6;
    const int quad = lane >> 4, l15 = lane & 15;
    const int m0 = blockIdx.x * 64 + wv * 16;
    const int n0 = blockIdx.y * 64;
    const ushort* ap = Ob + (size_t)(blockIdx.x * 4 + wv) * 4096 + l15 * 8;
    const ushort* bp = wb + (size_t)(blockIdx.y * 4) * 4096 + l15 * 8;

    f32x4 acc[4] = {};
    for (int ks = 0; ks < 8; ks++) {
        const int kdi = (ks * 4 + quad) * 128;
        bf16x8 af = *(const bf16x8*)(ap + kdi);
#pragma unroll
        for (int nt = 0; nt < 4; nt++) {
            bf16x8 bfr = *(const bf16x8*)(bp + nt * 4096 + kdi);
            acc[nt] = __builtin_amdgcn_mfma_f32_16x16x32_bf16(af, bfr, acc[nt], 0, 0, 0);
        }
    }
#pragma unroll
    for (int nt = 0; nt < 4; nt++) {
        const int j = n0 + nt * 16 + l15;
        const float bias = b[j];
#pragma unroll
        for (int r = 0; r < 4; r++) {
            const int orow = m0 + quad * 4 + r;
            out[orow * D + j] = acc[nt][r] + bias;
        }
    }
}

extern "C" void kernel_launch(void* const* d_in, const int* in_sizes, int n_in,
                              void* d_out, int out_size, void* d_ws, size_t ws_size,
                              hipStream_t stream) {
    const float* x     = (const float*)d_in[0];
    const int*   mask  = (const int*)d_in[1];
    const float* in_w  = (const float*)d_in[2];
    const float* in_b  = (const float*)d_in[3];
    const float* out_w = (const float*)d_in[4];
    const float* out_b = (const float*)d_in[5];
    const float* eb    = (const float*)d_in[6];

    ushort* ws = (ushort*)d_ws;
    ushort* Qb  = ws;
    ushort* Kb  = Qb + H * L * DH;             // sigma-permuted rows
    ushort* Vt  = Kb + H * L * DH;
    ushort* xb  = Vt + H * L * DH;             // x bf16 FM (qkv staging)
    ushort* wib = xb + L * D;
    ushort* wob = wib + 3 * D * D;
    unsigned char* m2 = (unsigned char*)(wob + D * D);   // 16 MB pair-index stream
    ushort* Ob = (ushort*)(m2 + (size_t)L * L);          // normalized bf16 attn out (FM)
    float* out = (float*)d_out;

    pack_kernel<<<dim3(1152), 256, 0, stream>>>(mask, x, in_w, out_w,
                                                (unsigned int*)m2, xb, wib, wob);
    qkv_kernel<<<dim3(64, 12), 256, 0, stream>>>(xb, wib, in_b, Qb, Kb, Vt);
    attn_kernel<<<dim3(1024), 512, 0, stream>>>(Qb, Kb, Vt, m2, eb, Ob);
    oproj_kernel<<<dim3(64, 4), 256, 0, stream>>>(Ob, wob, out_b, out);
}

// Round 9
// 170.467 us; speedup vs baseline: 1.1089x; 1.0108x over previous
//
#include <hip/hip_runtime.h>
#include <hip/hip_bf16.h>
#include <string.h>

#define L 4096
#define D 256
#define H 8
#define DH 32

typedef __attribute__((ext_vector_type(8))) short bf16x8;
typedef __attribute__((ext_vector_type(4))) float f32x4;

#define LOG2E 1.4426950408889634f
#define RS (0.17677669529663688f * LOG2E)   // 1/sqrt(DH) * log2(e), folded into Q

__device__ __forceinline__ ushort f2bf(float f) {
    union { float f; unsigned int i; } v; v.f = f;
    unsigned int x = v.i;
    return (ushort)((x + 0x7fffu + ((x >> 16) & 1u)) >> 16);   // RNE
}
__device__ __forceinline__ bf16x8 cvt8(const float* p) {
    float4 a = *(const float4*)p;
    float4 b = *(const float4*)(p + 4);
    bf16x8 r;
    r[0] = (short)f2bf(a.x); r[1] = (short)f2bf(a.y);
    r[2] = (short)f2bf(a.z); r[3] = (short)f2bf(a.w);
    r[4] = (short)f2bf(b.x); r[5] = (short)f2bf(b.y);
    r[6] = (short)f2bf(b.z); r[7] = (short)f2bf(b.w);
    return r;
}
// pack two fp32 -> bf16x2 dword; native v_cvt_pk_bf16_f32 on gfx950
__device__ __forceinline__ unsigned int pkbf(float a, float b) {
    float2 t; t.x = a; t.y = b;
    __hip_bfloat162 r = __float22bfloat162_rn(t);
    unsigned int u; memcpy(&u, &r, 4);
    return u;
}
__device__ __forceinline__ float uaf(unsigned int u) {
    union { unsigned int u; float f; } v; v.u = u; return v.f;
}

// sigma: logical key u (0..63) -> K storage row within its 64-block.
__device__ __forceinline__ int ksig(int u) {
    return 32 * (u >> 5) + 16 * ((u >> 2) & 1) + 4 * ((u >> 3) & 3) + (u & 3);
}

// Fragment-major (FM) layout for MFMA operand matrices (R rows x C cols bf16):
//   elem(r,c) at ((r>>4)*(C/8) + (c>>3))*128 + (r&15)*8 + (c&7)
// A wave's fragment load is ONE contiguous 1KB transaction (R8: -14.5 us).

// ---------------- Kernel 0: prepack (identical to R8) ----------------
__global__ __launch_bounds__(256) void pack_kernel(
        const int* __restrict__ mask, const float* __restrict__ x,
        const float* __restrict__ wi, const float* __restrict__ wo,
        unsigned int* __restrict__ m2, ushort* __restrict__ xb,
        ushort* __restrict__ wib, ushort* __restrict__ wob)
{
    const int b = blockIdx.x;
    const int tid = threadIdx.x;
    if (b < 512) {
        __shared__ unsigned int rb[8 * 1025];
        const int4* src = (const int4*)(mask + (size_t)b * 8 * 4096);
#pragma unroll
        for (int i = 0; i < 32; i++) {
            const int g = i * 256 + tid;
            int4 v = src[g];
            rb[(g >> 10) * 1025 + (g & 1023)] =
                ((unsigned int)(v.x & 15) << 4)  | ((unsigned int)(v.y & 15) << 12) |
                ((unsigned int)(v.z & 15) << 20) | ((unsigned int)(v.w & 15) << 28);
        }
        __syncthreads();
        const int t = b >> 1, half = b & 1;
#pragma unroll
        for (int i = 0; i < 32; i++) {
            const int dd = i * 256 + tid;
            const int nt = dd & 3, s = (dd >> 2) & 7, qd = (dd >> 5) & 3, kt = dd >> 7;
            const unsigned int w =
                rb[s * 1025 + kt * 16 + 8 * (nt >> 1) + 2 * qd + (nt & 1)];
            const unsigned int e0 = (w >> 4) & 15u, e1 = (w >> 12) & 15u;
            const unsigned int e2 = (w >> 20) & 15u, e3 = w >> 28;
            const unsigned int p01 = e0 * 14u + e1, p23 = e2 * 14u + e3;
            m2[(size_t)t * 16384 + kt * 256 + (qd * 16 + 8 * half + s) * 4 + nt] =
                (p01 * 68u) | ((p23 * 68u) << 16);
        }
    } else if (b < 1024) {
        const int g = (b - 512) * 256 + tid;
        const int l = g & 15, kd = (g >> 4) & 31, mg = g >> 9;
        ((bf16x8*)xb)[g] = cvt8(x + (mg * 16 + l) * 256 + kd * 8);
    } else if (b < 1120) {
        const int g = (b - 1024) * 256 + tid;           // 768x256 FM
        const int l = g & 15, kd = (g >> 4) & 31, mg = g >> 9;
        ((bf16x8*)wib)[g] = cvt8(wi + (mg * 16 + l) * 256 + kd * 8);
    } else {
        const int g = (b - 1120) * 256 + tid;           // 256x256 FM
        const int l = g & 15, kd = (g >> 4) & 31, mg = g >> 9;
        ((bf16x8*)wob)[g] = cvt8(wo + (mg * 16 + l) * 256 + kd * 8);
    }
}

// ---------------- Kernel 1: QKV projection, LDS-staged coalesced epilogue ----
// R8's epilogue did 16 scalar ushort stores/thread into transposed layouts:
// Vt writes were 2-byte scatters (64 sectors/wave-store, 16x amplification),
// Q/K 32B segments. Now: stage the 64x64 tile in LDS (bias+RS+ksig applied),
// then write destination-native contiguous order: Q/K = two 4KB region copies
// (1KB per wave-store), V = 32B column chunks.
__global__ __launch_bounds__(256) void qkv_kernel(
        const ushort* __restrict__ xb, const ushort* __restrict__ wb,
        const float* __restrict__ b,
        ushort* __restrict__ Qb, ushort* __restrict__ Kb, ushort* __restrict__ Vt)
{
    __shared__ ushort tile[64][72];   // 9.2 KB; row stride 144B (16B-aligned)

    const int lane = threadIdx.x & 63, wv = threadIdx.x >> 6;
    const int quad = lane >> 4, l15 = lane & 15;
    const int m0b = blockIdx.x * 64;
    const int by = blockIdx.y;            // 0-3: Q, 4-7: K, 8-11: V
    const int n0 = by * 64;
    const ushort* ap = xb + (size_t)(blockIdx.x * 4 + wv) * 4096 + l15 * 8;
    const ushort* bp = wb + (size_t)(by * 4) * 4096 + l15 * 8;

    f32x4 acc[4] = {};
    for (int ks = 0; ks < 8; ks++) {
        const int kdi = (ks * 4 + quad) * 128;
        bf16x8 af = *(const bf16x8*)(ap + kdi);
#pragma unroll
        for (int nt = 0; nt < 4; nt++) {
            bf16x8 bfr = *(const bf16x8*)(bp + nt * 4096 + kdi);
            acc[nt] = __builtin_amdgcn_mfma_f32_16x16x32_bf16(af, bfr, acc[nt], 0, 0, 0);
        }
    }

    const bool isQ = (by < 4), isK = (by >= 4) && (by < 8);
#pragma unroll
    for (int nt = 0; nt < 4; nt++) {
        const int c = nt * 16 + l15;
        const float bias = b[n0 + c];
#pragma unroll
        for (int r = 0; r < 4; r++) {
            const int lr = wv * 16 + quad * 4 + r;
            float val = acc[nt][r] + bias;
            if (isQ) val *= RS;
            tile[isK ? ksig(lr) : lr][c] = f2bf(val);
        }
    }
    __syncthreads();

    const int t = threadIdx.x;
    if (by < 8) {
        // two contiguous 4KB dest regions (col-halves hh); 128 threads each,
        // 2 chunks of 8 ushorts per thread; wave-store = 1KB contiguous.
        const int hh = t >> 7, i = t & 127;
        ushort* dst = isQ ? Qb + ((size_t)(by * 2 + hh) * L + m0b) * 32
                          : Kb + ((size_t)((by - 4) * 2 + hh) * L + m0b) * 32;
#pragma unroll
        for (int k = 0; k < 2; k++) {
            const int ci = i + k * 128;               // chunk: dest ushorts [ci*8, ci*8+8)
            const int row = ci >> 2, wc = (ci & 3) * 8;
            *(bf16x8*)(dst + ci * 8) = *(const bf16x8*)(&tile[row][hh * 32 + wc]);
        }
    } else {
        // V: dest column vc has 64 contiguous rows at Vt + vc*L + m0b.
        // thread t: col = t&63 (lanes span 64 cols -> LDS banks 2-way free),
        // rows (t>>6)*16..+15 -> one 32B contiguous store per thread.
        const int c = t & 63, rh = t >> 6;
        const int vc = n0 - 512 + c;
        ushort tmp[16];
#pragma unroll
        for (int r = 0; r < 16; r++) tmp[r] = tile[rh * 16 + r][c];
        ushort* dst = Vt + (size_t)vc * L + m0b + rh * 16;
        *(bf16x8*)dst       = *(const bf16x8*)tmp;
        *(bf16x8*)(dst + 8) = *(const bf16x8*)(tmp + 8);
    }
}

// ---------------- Kernel 2: register-resident flash attention (R8, unchanged) --
__global__ __launch_bounds__(512) void attn_kernel(
        const ushort* __restrict__ Qb, const ushort* __restrict__ Kb,
        const ushort* __restrict__ Vt, const unsigned char* __restrict__ m2,
        const float* __restrict__ edge_bias, ushort* __restrict__ Ob)
{
    __shared__ unsigned int lutp[196 * 17];   // 13.3 KB pair-LUT (bf16x2)
    __shared__ float red[7 * 576];            // 16.1 KB reduction slots

    const int tid = threadIdx.x;
    const int lane = tid & 63, wv = tid >> 6;
    const int quad = lane >> 4, l15 = lane & 15;

    // qg-grouped XCD decode: all 8 heads of a q-group share bid%8 -> same XCD.
    const int bid = blockIdx.x;
    const int xr = bid & 7, j = bid >> 3;          // j in [0,128)
    const int qg = xr * 16 + (j >> 3);             // q-group 0..127, q0 = qg*32
    const int h  = j & 7;
    const int q0 = qg * 32;
    const int kt0 = wv * 8;                        // this wave's 8-kt slice

    // per-head pair-LUT: entry p, copy c at dword 17p+c
    for (int p = tid; p < 196; p += 512) {
        const int e1 = (p * 2341) >> 15;           // p / 14 for p < 196
        const int e2 = p - 14 * e1;
        const unsigned int v = pkbf(edge_bias[e1 * H + h] * LOG2E,
                                    edge_bias[e2 * H + h] * LOG2E);
#pragma unroll
        for (int c = 0; c < 17; c++) lutp[p * 17 + c] = v;
    }
    __syncthreads();

    const bf16x8 qfA = *(const bf16x8*)(Qb + (h * L + q0 + l15) * DH + quad * 8);
    const bf16x8 qfB = *(const bf16x8*)(Qb + (h * L + q0 + 16 + l15) * DH + quad * 8);
    const char* lutb = (const char*)lutp + l15 * 4;   // per-lane copy base

    const ushort* Kl = Kb + h * L * DH + kt0 * 64 * DH + l15 * DH + quad * 8;
    const ushort* Va = Vt + (h * DH + l15) * L + kt0 * 64 + quad * 8;
    const ushort* Vb = Vt + (h * DH + 16 + l15) * L + kt0 * 64 + quad * 8;
    const unsigned char* mpA = m2 + (size_t)(2 * qg) * 65536
                             + (size_t)kt0 * 1024 + lane * 16;
    const unsigned char* mpB = mpA + 65536;

    f32x4 o0A = {}, o1A = {}, osA = {};
    f32x4 o0B = {}, o1B = {}, osB = {};
    bf16x8 ones;
#pragma unroll
    for (int i = 0; i < 8; i++) ones[i] = (short)0x3F80;   // 1.0 bf16

    for (int kt = 0; kt < 8; kt++) {
        const int4 mA4 = *(const int4*)(mpA + kt * 1024);
        const int4 mB4 = *(const int4*)(mpB + kt * 1024);
        const unsigned int mA[4] = {(unsigned int)mA4.x, (unsigned int)mA4.y,
                                    (unsigned int)mA4.z, (unsigned int)mA4.w};
        const unsigned int mB[4] = {(unsigned int)mB4.x, (unsigned int)mB4.y,
                                    (unsigned int)mB4.z, (unsigned int)mB4.w};

#pragma unroll
        for (int half = 0; half < 2; half++) {
            union { bf16x8 v; unsigned int u[4]; } pfA, pfB;
#pragma unroll
            for (int nt2 = 0; nt2 < 2; nt2++) {
                const int nt = half * 2 + nt2;
                bf16x8 kf = *(const bf16x8*)(Kl + (kt * 64 + nt * 16) * DH);
                f32x4 z = {};
                f32x4 svA = __builtin_amdgcn_mfma_f32_16x16x32_bf16(kf, qfA, z, 0, 0, 0);
                f32x4 svB = __builtin_amdgcn_mfma_f32_16x16x32_bf16(kf, qfB, z, 0, 0, 0);
                const unsigned int wA = mA[nt], wB = mB[nt];
                const unsigned int dA0 = *(const unsigned int*)(lutb + (wA & 0xFFFFu));
                const unsigned int dA1 = *(const unsigned int*)(lutb + (wA >> 16));
                const unsigned int dB0 = *(const unsigned int*)(lutb + (wB & 0xFFFFu));
                const unsigned int dB1 = *(const unsigned int*)(lutb + (wB >> 16));
                float a0 = __builtin_amdgcn_exp2f(svA[0] + uaf(dA0 << 16));
                float a1 = __builtin_amdgcn_exp2f(svA[1] + uaf(dA0 & 0xFFFF0000u));
                float a2 = __builtin_amdgcn_exp2f(svA[2] + uaf(dA1 << 16));
                float a3 = __builtin_amdgcn_exp2f(svA[3] + uaf(dA1 & 0xFFFF0000u));
                float b0 = __builtin_amdgcn_exp2f(svB[0] + uaf(dB0 << 16));
                float b1 = __builtin_amdgcn_exp2f(svB[1] + uaf(dB0 & 0xFFFF0000u));
                float b2 = __builtin_amdgcn_exp2f(svB[2] + uaf(dB1 << 16));
                float b3 = __builtin_amdgcn_exp2f(svB[3] + uaf(dB1 & 0xFFFF0000u));
                pfA.u[nt2 * 2]     = pkbf(a0, a1);
                pfA.u[nt2 * 2 + 1] = pkbf(a2, a3);
                pfB.u[nt2 * 2]     = pkbf(b0, b1);
                pfB.u[nt2 * 2 + 1] = pkbf(b2, b3);
            }
            bf16x8 va = *(const bf16x8*)(Va + kt * 64 + half * 32);
            bf16x8 vb = *(const bf16x8*)(Vb + kt * 64 + half * 32);
            __builtin_amdgcn_s_setprio(1);
            o0A = __builtin_amdgcn_mfma_f32_16x16x32_bf16(va,   pfA.v, o0A, 0, 0, 0);
            o1A = __builtin_amdgcn_mfma_f32_16x16x32_bf16(vb,   pfA.v, o1A, 0, 0, 0);
            osA = __builtin_amdgcn_mfma_f32_16x16x32_bf16(ones, pfA.v, osA, 0, 0, 0);
            o0B = __builtin_amdgcn_mfma_f32_16x16x32_bf16(va,   pfB.v, o0B, 0, 0, 0);
            o1B = __builtin_amdgcn_mfma_f32_16x16x32_bf16(vb,   pfB.v, o1B, 0, 0, 0);
            osB = __builtin_amdgcn_mfma_f32_16x16x32_bf16(ones, pfB.v, osB, 0, 0, 0);
            __builtin_amdgcn_s_setprio(0);
        }
    }

    // FM Ob write addresses: row r=q0+l15 (mg=2qg), cols h*32 + {quad*4, 16+quad*4}
    ushort* obase = Ob + (size_t)(2 * qg) * 4096 + l15 * 8 + (quad & 1) * 4;
    ushort* or0A = obase + (h * 4 + (quad >> 1)) * 128;
    ushort* or1A = obase + (h * 4 + 2 + (quad >> 1)) * 128;
    ushort* or0B = or0A + 4096;
    ushort* or1B = or1A + 4096;

    // ---- two-phase in-block KT reduction (reuses red[] for A then B) ----
    if (wv > 0) {
        float* s = red + (wv - 1) * 576;
        *(f32x4*)(s +       lane * 4) = o0A;
        *(f32x4*)(s + 256 + lane * 4) = o1A;
        s[512 + lane] = osA[0];
    }
    __syncthreads();
    if (wv == 0) {
#pragma unroll
        for (int sl = 0; sl < 7; sl++) {
            const float* s = red + sl * 576;
            o0A += *(const f32x4*)(s +       lane * 4);
            o1A += *(const f32x4*)(s + 256 + lane * 4);
            osA[0] += s[512 + lane];
        }
        const float invA = 1.f / osA[0];
        uint2 u;
        u.x = pkbf(o0A[0] * invA, o0A[1] * invA);
        u.y = pkbf(o0A[2] * invA, o0A[3] * invA);
        *(uint2*)or0A = u;
        u.x = pkbf(o1A[0] * invA, o1A[1] * invA);
        u.y = pkbf(o1A[2] * invA, o1A[3] * invA);
        *(uint2*)or1A = u;
    }
    __syncthreads();
    if (wv > 0) {
        float* s = red + (wv - 1) * 576;
        *(f32x4*)(s +       lane * 4) = o0B;
        *(f32x4*)(s + 256 + lane * 4) = o1B;
        s[512 + lane] = osB[0];
    }
    __syncthreads();
    if (wv == 0) {
#pragma unroll
        for (int sl = 0; sl < 7; sl++) {
            const float* s = red + sl * 576;
            o0B += *(const f32x4*)(s +       lane * 4);
            o1B += *(const f32x4*)(s + 256 + lane * 4);
            osB[0] += s[512 + lane];
        }
        const float invB = 1.f / osB[0];
        uint2 u;
        u.x = pkbf(o0B[0] * invB, o0B[1] * invB);
        u.y = pkbf(o0B[2] * invB, o0B[3] * invB);
        *(uint2*)or0B = u;
        u.x = pkbf(o1B[0] * invB, o1B[1] * invB);
        u.y = pkbf(o1B[2] * invB, o1B[3] * invB);
        *(uint2*)or1B = u;
    }
}

// ---------------- Kernel 3: output projection GEMM, 16x16 per wave ----------
// R8 grid (64,4) = 1 wave/SIMD (no latency hiding). Now 16x16 tiles/wave:
// grid (64,16) = 4096 waves = 16 waves/CU. Ob/wob tiny -> redundant B loads
// are L2-served.
__global__ __launch_bounds__(256) void oproj_kernel(
        const ushort* __restrict__ Ob, const ushort* __restrict__ wb,
        const float* __restrict__ b, float* __restrict__ out)
{
    const int lane = threadIdx.x & 63, wv = threadIdx.x >> 6;
    const int quad = lane >> 4, l15 = lane & 15;
    const int m0 = blockIdx.x * 64 + wv * 16;
    const int n0 = blockIdx.y * 16;
    const ushort* ap = Ob + (size_t)(blockIdx.x * 4 + wv) * 4096 + l15 * 8;
    const ushort* bp = wb + (size_t)blockIdx.y * 4096 + l15 * 8;

    f32x4 acc = {};
    for (int ks = 0; ks < 8; ks++) {
        const int kdi = (ks * 4 + quad) * 128;
        bf16x8 af  = *(const bf16x8*)(ap + kdi);
        bf16x8 bfr = *(const bf16x8*)(bp + kdi);
        acc = __builtin_amdgcn_mfma_f32_16x16x32_bf16(af, bfr, acc, 0, 0, 0);
    }
    const int j = n0 + l15;
    const float bias = b[j];
#pragma unroll
    for (int r = 0; r < 4; r++) {
        out[(m0 + quad * 4 + r) * D + j] = acc[r] + bias;
    }
}

extern "C" void kernel_launch(void* const* d_in, const int* in_sizes, int n_in,
                              void* d_out, int out_size, void* d_ws, size_t ws_size,
                              hipStream_t stream) {
    const float* x     = (const float*)d_in[0];
    const int*   mask  = (const int*)d_in[1];
    const float* in_w  = (const float*)d_in[2];
    const float* in_b  = (const float*)d_in[3];
    const float* out_w = (const float*)d_in[4];
    const float* out_b = (const float*)d_in[5];
    const float* eb    = (const float*)d_in[6];

    ushort* ws = (ushort*)d_ws;
    ushort* Qb  = ws;
    ushort* Kb  = Qb + H * L * DH;             // sigma-permuted rows
    ushort* Vt  = Kb + H * L * DH;
    ushort* xb  = Vt + H * L * DH;             // x bf16 FM (qkv staging)
    ushort* wib = xb + L * D;
    ushort* wob = wib + 3 * D * D;
    unsigned char* m2 = (unsigned char*)(wob + D * D);   // 16 MB pair-index stream
    ushort* Ob = (ushort*)(m2 + (size_t)L * L);          // normalized bf16 attn out (FM)
    float* out = (float*)d_out;

    pack_kernel<<<dim3(1152), 256, 0, stream>>>(mask, x, in_w, out_w,
                                                (unsigned int*)m2, xb, wib, wob);
    qkv_kernel<<<dim3(64, 12), 256, 0, stream>>>(xb, wib, in_b, Qb, Kb, Vt);
    attn_kernel<<<dim3(1024), 512, 0, stream>>>(Qb, Kb, Vt, m2, eb, Ob);
    oproj_kernel<<<dim3(64, 16), 256, 0, stream>>>(Ob, wob, out_b, out);
}